// Round 2
// 395.535 us; speedup vs baseline: 1.0021x; 1.0021x over previous
//
#include <hip/hip_runtime.h>

// Problem constants (from reference)
#define NNZ        524288
#define DDIM       256
#define N_MENTIONS 65536

// Native clang vector type — layout-identical to HIP float4, accepted by
// __builtin_nontemporal_store/load (HIP_vector_type class is rejected).
typedef float f32x4 __attribute__((ext_vector_type(4)));

// ---------------------------------------------------------------------------
// Kernel 1: build row_start[0 .. N_MENTIONS] in d_ws from sorted spm_rows.
// Thread j (0..NNZ) writes row_start[r] = j for all r in (prev, cur], where
// prev = spm_rows[j-1] (-1 for j==0), cur = spm_rows[j] (N_MENTIONS for j==NNZ).
// Union over j covers [0, N_MENTIONS] exactly once (disjoint ranges), so the
// 0xAA-poisoned workspace is fully overwritten every call.
// ---------------------------------------------------------------------------
__global__ __launch_bounds__(256) void build_row_start_kernel(
    const int* __restrict__ spm_rows,   // [NNZ] sorted
    int*       __restrict__ row_start)  // [N_MENTIONS + 1]
{
    const int j = blockIdx.x * blockDim.x + threadIdx.x;
    if (j > NNZ) return;
    const int cur  = (j < NNZ) ? spm_rows[j] : N_MENTIONS;
    const int prev = (j > 0)   ? spm_rows[j - 1] : -1;
    for (int r = prev + 1; r <= cur; ++r) row_start[r] = j;
}

// ---------------------------------------------------------------------------
// Kernel 2: one wave per mention row. Lane l owns float4 columns [4l, 4l+4).
// Codes/vals for up to 64 nnz are lane-loaded once (nontemporal — stream-once
// data), then consumed via v_readlane: the row index is wave-uniform, so the
// gather base lives in SGPRs and each gather is a single
// global_load_dwordx4 v, v_laneoff, s[rowbase] with no per-lane 64-bit VALU
// address chain. That frees enough VGPRs to keep 8 independent 1-KiB row
// reads in flight per wave at 8 waves/EU (<=64 VGPR, pinned by launch_bounds).
// Out store is nontemporal: 64 MiB of streaming writes must not evict
// token_ft (256 MiB, exactly LLC-sized) from L2/L3.
// ---------------------------------------------------------------------------
__device__ __forceinline__ const f32x4* ft_row(const float* token_ft, int code_l, int i)
{
    // code_l holds lane i's token code; i is wave-uniform -> result is SGPR.
    const int c = __builtin_amdgcn_readlane(code_l, i);
    return (const f32x4*)(token_ft + ((size_t)c << 8));   // * DDIM floats
}

__device__ __forceinline__ float val_lane(int val_bits_l, int i)
{
    return __int_as_float(__builtin_amdgcn_readlane(val_bits_l, i));
}

__global__ __launch_bounds__(256, 8) void mention_csr_kernel(
    const float* __restrict__ token_ft,   // [N_TOKENS, 256]
    const int*   __restrict__ token_code, // [NNZ]
    const float* __restrict__ spm_vals,   // [NNZ]
    const int*   __restrict__ row_start,  // [N_MENTIONS + 1]
    float*       __restrict__ out)        // [N_MENTIONS, 256]
{
    const int wave = threadIdx.x >> 6;            // 0..3
    const int lane = threadIdx.x & 63;
    const int row  = (blockIdx.x << 2) + wave;    // mention row

    const int start = row_start[row];
    const int end   = row_start[row + 1];

    f32x4 acc0 = {0.f, 0.f, 0.f, 0.f};
    f32x4 acc1 = {0.f, 0.f, 0.f, 0.f};

    for (int base = start; base < end; base += 64) {
        const int count = min(64, end - base);
        int code_l = 0;
        int vbits_l = 0;
        if (lane < count) {
            code_l  = __builtin_nontemporal_load(token_code + base + lane);
            vbits_l = __builtin_nontemporal_load((const int*)spm_vals + base + lane);
        }

        int i = 0;
        // 8-deep gather issue: all 8 loads are scalar-based + lane offset,
        // independent, so 8 are outstanding per wait.
        for (; i + 8 <= count; i += 8) {
            const f32x4* p0 = ft_row(token_ft, code_l, i + 0);
            const f32x4* p1 = ft_row(token_ft, code_l, i + 1);
            const f32x4* p2 = ft_row(token_ft, code_l, i + 2);
            const f32x4* p3 = ft_row(token_ft, code_l, i + 3);
            const f32x4* p4 = ft_row(token_ft, code_l, i + 4);
            const f32x4* p5 = ft_row(token_ft, code_l, i + 5);
            const f32x4* p6 = ft_row(token_ft, code_l, i + 6);
            const f32x4* p7 = ft_row(token_ft, code_l, i + 7);
            const f32x4 f0 = p0[lane];
            const f32x4 f1 = p1[lane];
            const f32x4 f2 = p2[lane];
            const f32x4 f3 = p3[lane];
            const f32x4 f4 = p4[lane];
            const f32x4 f5 = p5[lane];
            const f32x4 f6 = p6[lane];
            const f32x4 f7 = p7[lane];
            const float v0 = val_lane(vbits_l, i + 0);
            const float v1 = val_lane(vbits_l, i + 1);
            const float v2 = val_lane(vbits_l, i + 2);
            const float v3 = val_lane(vbits_l, i + 3);
            const float v4 = val_lane(vbits_l, i + 4);
            const float v5 = val_lane(vbits_l, i + 5);
            const float v6 = val_lane(vbits_l, i + 6);
            const float v7 = val_lane(vbits_l, i + 7);
            acc0 += f0 * v0;
            acc1 += f1 * v1;
            acc0 += f2 * v2;
            acc1 += f3 * v3;
            acc0 += f4 * v4;
            acc1 += f5 * v5;
            acc0 += f6 * v6;
            acc1 += f7 * v7;
        }
        if (i + 4 <= count) {
            const f32x4* p0 = ft_row(token_ft, code_l, i + 0);
            const f32x4* p1 = ft_row(token_ft, code_l, i + 1);
            const f32x4* p2 = ft_row(token_ft, code_l, i + 2);
            const f32x4* p3 = ft_row(token_ft, code_l, i + 3);
            const f32x4 f0 = p0[lane];
            const f32x4 f1 = p1[lane];
            const f32x4 f2 = p2[lane];
            const f32x4 f3 = p3[lane];
            const float v0 = val_lane(vbits_l, i + 0);
            const float v1 = val_lane(vbits_l, i + 1);
            const float v2 = val_lane(vbits_l, i + 2);
            const float v3 = val_lane(vbits_l, i + 3);
            acc0 += f0 * v0;
            acc1 += f1 * v1;
            acc0 += f2 * v2;
            acc1 += f3 * v3;
            i += 4;
        }
        for (; i < count; ++i) {
            const f32x4* p = ft_row(token_ft, code_l, i);
            const f32x4 f = p[lane];
            const float v = val_lane(vbits_l, i);
            acc0 += f * v;
        }
    }

    acc0 += acc1;
    // Always store (zeros for empty segments — d_out is poisoned by harness).
    // Nontemporal: streaming output must not evict token_ft from L2/L3.
    f32x4* outp = (f32x4*)(out + (size_t)row * DDIM) + lane;
    __builtin_nontemporal_store(acc0, outp);
}

// ---------------------------------------------------------------------------
// Fallback (ws too small): original binary-search kernel. Kept for safety.
// ---------------------------------------------------------------------------
__global__ __launch_bounds__(256) void mention_segsum_kernel(
    const float* __restrict__ token_ft,
    const int*   __restrict__ token_code,
    const int*   __restrict__ spm_rows,
    const float* __restrict__ spm_vals,
    float*       __restrict__ out)
{
    const int wave = threadIdx.x >> 6;
    const int lane = threadIdx.x & 63;
    const int row  = (blockIdx.x << 2) + wave;

    int lo = 0, hi = NNZ;
    while (lo < hi) {
        int mid = (lo + hi) >> 1;
        if (spm_rows[mid] < row) lo = mid + 1; else hi = mid;
    }
    const int start = lo;
    hi = NNZ;
    while (lo < hi) {
        int mid = (lo + hi) >> 1;
        if (spm_rows[mid] < row + 1) lo = mid + 1; else hi = mid;
    }
    const int end = lo;

    float4 acc = make_float4(0.f, 0.f, 0.f, 0.f);
    for (int k = start; k < end; ++k) {
        const int   code = token_code[k];
        const float v    = spm_vals[k];
        const float4 ft = ((const float4*)(token_ft + (size_t)code * DDIM))[lane];
        acc.x += ft.x * v; acc.y += ft.y * v; acc.z += ft.z * v; acc.w += ft.w * v;
    }
    ((float4*)(out + (size_t)row * DDIM))[lane] = acc;
}

extern "C" void kernel_launch(void* const* d_in, const int* in_sizes, int n_in,
                              void* d_out, int out_size, void* d_ws, size_t ws_size,
                              hipStream_t stream) {
    const float* token_ft   = (const float*)d_in[0];
    const int*   token_code = (const int*)d_in[1];
    const int*   spm_rows   = (const int*)d_in[2];
    const float* spm_vals   = (const float*)d_in[3];
    float*       out        = (float*)d_out;

    const size_t need = (size_t)(N_MENTIONS + 1) * sizeof(int);
    if (ws_size >= need) {
        int* row_start = (int*)d_ws;
        // Kernel 1: NNZ+1 threads
        build_row_start_kernel<<<(NNZ + 1 + 255) / 256, 256, 0, stream>>>(
            spm_rows, row_start);
        // Kernel 2: 4 rows (waves) per 256-thread block
        mention_csr_kernel<<<N_MENTIONS / 4, 256, 0, stream>>>(
            token_ft, token_code, spm_vals, row_start, out);
    } else {
        mention_segsum_kernel<<<N_MENTIONS / 4, 256, 0, stream>>>(
            token_ft, token_code, spm_rows, spm_vals, out);
    }
}